// Round 2
// baseline (168.132 us; speedup 1.0000x reference)
//
#include <hip/hip_runtime.h>
#include <math.h>

#define D 768
#define T 128

// ln(0.9*0.99) = ln(0.891)
#define LN_ETA_DECAY (-0.11541085151132775f)

// K1: P = keys @ W^T, one wave per output row o. 192 blocks x 256 threads.
// Emits E[t,o] = 2*c[t]*(P[t,o]-V[t,o]) and errb[t,o] = P[t,o]+b[o]-V[t,o]
// into workspace (fp32), and writes b_new / mb_new directly.
__global__ __launch_bounds__(256) void k1_proj(
    const float* __restrict__ W,
    const float* __restrict__ bparam,
    const float* __restrict__ keys,
    const float* __restrict__ values,
    const float* __restrict__ mb,
    float* __restrict__ E,
    float* __restrict__ errb_ws,
    float* __restrict__ b_new,
    float* __restrict__ mb_new,
    float pow_eta_T, float beta_total)
{
    const int wave = threadIdx.x >> 6;
    const int lane = threadIdx.x & 63;
    const int o = blockIdx.x * 4 + wave;

    // Preload W row o into registers: lane covers cols 4*lane + 256*j
    float wreg[12];
    const float* wrow = W + o * D;
    const int base = 4 * lane;
    #pragma unroll
    for (int j = 0; j < 3; ++j) {
        float4 wv = *reinterpret_cast<const float4*>(wrow + base + 256 * j);
        wreg[4 * j + 0] = wv.x;
        wreg[4 * j + 1] = wv.y;
        wreg[4 * j + 2] = wv.z;
        wreg[4 * j + 3] = wv.w;
    }
    const float b0 = bparam[o];

    float mbacc = 0.f;  // lane-partial of sum_t c[t]*errb[t,o]
    for (int t = 0; t < T; ++t) {
        const float* krow = keys + t * D;
        float acc = 0.f;
        #pragma unroll
        for (int j = 0; j < 3; ++j) {
            float4 kv = *reinterpret_cast<const float4*>(krow + base + 256 * j);
            acc += kv.x * wreg[4 * j + 0] + kv.y * wreg[4 * j + 1]
                 + kv.z * wreg[4 * j + 2] + kv.w * wreg[4 * j + 3];
        }
        // butterfly: all lanes end with the full dot product
        #pragma unroll
        for (int s = 32; s >= 1; s >>= 1) acc += __shfl_xor(acc, s, 64);

        if (lane == (t & 63)) {
            const float v = values[t * D + o];
            const float errW = acc - v;
            const float errb = acc + b0 - v;
            const float ct = 0.01f * expf((float)(127 - t) * LN_ETA_DECAY);
            E[t * D + o] = 2.f * ct * errW;
            errb_ws[t * D + o] = errb;
            mbacc += ct * errb;
        }
    }
    #pragma unroll
    for (int s = 32; s >= 1; s >>= 1) mbacc += __shfl_xor(mbacc, s, 64);
    if (lane == 0) {
        const float nmb = pow_eta_T * mb[o] - 2.f * mbacc;
        mb_new[o] = nmb;
        b_new[o]  = beta_total * b0 + nmb;
    }
}

// K2: G = E^T @ keys (768x768, K=128), fused epilogue:
//   mW_new = pow_eta_T*mW - G ; W_new = beta_total*W + mW_new
// 144 blocks (12x12 tiles of 64x64), 256 threads, each thread 4x4 outputs.
__global__ __launch_bounds__(256) void k2_gemm(
    const float* __restrict__ E,
    const float* __restrict__ keys,
    const float* __restrict__ W,
    const float* __restrict__ mW,
    float* __restrict__ W_new,
    float* __restrict__ mW_new,
    float pow_eta_T, float beta_total)
{
    __shared__ float sE[T][64];  // 32 KB: E[t, bo..bo+63]
    __shared__ float sK[T][64];  // 32 KB: keys[t, bi..bi+63]

    const int bo = (blockIdx.x / 12) * 64;
    const int bi = (blockIdx.x % 12) * 64;

    const int tc = threadIdx.x & 15;   // float4-column within tile
    const int tr = threadIdx.x >> 4;   // row base

    #pragma unroll
    for (int it = 0; it < 8; ++it) {
        const int row = tr + 16 * it;
        *reinterpret_cast<float4*>(&sE[row][tc * 4]) =
            *reinterpret_cast<const float4*>(&E[row * D + bo + tc * 4]);
        *reinterpret_cast<float4*>(&sK[row][tc * 4]) =
            *reinterpret_cast<const float4*>(&keys[row * D + bi + tc * 4]);
    }
    __syncthreads();

    const int ty = threadIdx.x >> 4;   // 0..15 -> o sub-tile
    const int tx = threadIdx.x & 15;   // 0..15 -> i sub-tile
    const int olocal = (ty & 3) * 4 + (ty >> 2) * 16;

    float acc[4][4] = {{0.f}};
    #pragma unroll 4
    for (int k = 0; k < T; ++k) {
        float4 e  = *reinterpret_cast<const float4*>(&sE[k][olocal]);
        float4 kk = *reinterpret_cast<const float4*>(&sK[k][tx * 4]);
        const float ev[4] = {e.x, e.y, e.z, e.w};
        const float kv[4] = {kk.x, kk.y, kk.z, kk.w};
        #pragma unroll
        for (int a = 0; a < 4; ++a)
            #pragma unroll
            for (int b = 0; b < 4; ++b)
                acc[a][b] += ev[a] * kv[b];
    }

    #pragma unroll
    for (int a = 0; a < 4; ++a) {
        const int o = bo + olocal + a;
        const int i = bi + tx * 4;
        float4 wv = *reinterpret_cast<const float4*>(&W[o * D + i]);
        float4 mv = *reinterpret_cast<const float4*>(&mW[o * D + i]);
        float4 nmv, wn;
        nmv.x = pow_eta_T * mv.x - acc[a][0];
        nmv.y = pow_eta_T * mv.y - acc[a][1];
        nmv.z = pow_eta_T * mv.z - acc[a][2];
        nmv.w = pow_eta_T * mv.w - acc[a][3];
        wn.x = beta_total * wv.x + nmv.x;
        wn.y = beta_total * wv.y + nmv.y;
        wn.z = beta_total * wv.z + nmv.z;
        wn.w = beta_total * wv.w + nmv.w;
        *reinterpret_cast<float4*>(&mW_new[o * D + i]) = nmv;
        *reinterpret_cast<float4*>(&W_new[o * D + i])  = wn;
    }
}

// K3: losses[t] = mean_o errb[t,o]^2. 128 blocks x 64 threads.
__global__ __launch_bounds__(64) void k3_losses(
    const float* __restrict__ errb_ws,
    float* __restrict__ losses)
{
    const int t = blockIdx.x;
    const int lane = threadIdx.x;
    float s = 0.f;
    #pragma unroll
    for (int j = 0; j < 12; ++j) {
        const float e = errb_ws[t * D + lane + 64 * j];
        s += e * e;
    }
    #pragma unroll
    for (int sft = 32; sft >= 1; sft >>= 1) s += __shfl_xor(s, sft, 64);
    if (lane == 0) losses[t] = s * (1.f / 768.f);
}

extern "C" void kernel_launch(void* const* d_in, const int* in_sizes, int n_in,
                              void* d_out, int out_size, void* d_ws, size_t ws_size,
                              hipStream_t stream) {
    const float* W      = (const float*)d_in[0];
    const float* bparam = (const float*)d_in[1];
    const float* keys   = (const float*)d_in[2];
    const float* values = (const float*)d_in[3];
    const float* mW     = (const float*)d_in[4];
    const float* mb     = (const float*)d_in[5];

    float* out = (float*)d_out;
    float* W_new   = out;                       // 768*768
    float* b_new   = out + 589824;              // 768
    float* mW_new  = out + 590592;              // 768*768
    float* mb_new  = out + 1180416;             // 768
    float* losses  = out + 1181184;             // 128

    float* E       = (float*)d_ws;          // 128*768 fp32
    float* errb_ws = E + T * D;             // 128*768 fp32

    const float pow_eta_T  = (float)pow(0.9, 128);   // 0.9^128
    const float beta_total = (float)pow(0.99, 128);  // 0.99^128

    k1_proj<<<192, 256, 0, stream>>>(W, bparam, keys, values, mb,
                                     E, errb_ws, b_new, mb_new,
                                     pow_eta_T, beta_total);
    k2_gemm<<<144, 256, 0, stream>>>(E, keys, W, mW, W_new, mW_new,
                                     pow_eta_T, beta_total);
    k3_losses<<<128, 64, 0, stream>>>(errb_ws, losses);
}

// Round 3
// 111.273 us; speedup vs baseline: 1.5110x; 1.5110x over previous
//
#include <hip/hip_runtime.h>
#include <math.h>

#define D 768
#define T 128

// ln(0.9*0.99) = ln(0.891)
#define LN_ETA_DECAY (-0.11541085151132775f)

// ---------------------------------------------------------------------------
// K1: split-K partial GEMM  P = keys @ W^T   (M=128 t, N=768 o, K=768)
// grid = (12 o-tiles, KC k-chunks), 256 threads.
// Block computes partial P[0:128, obase:obase+64] over k in [kbase, kbase+chunkLen)
// and stores to Ppart[blockIdx.y][t][o].
// ---------------------------------------------------------------------------
__global__ __launch_bounds__(256) void k1_pgemm(
    const float* __restrict__ W,
    const float* __restrict__ keys,
    float* __restrict__ Ppart,
    int chunkLen)
{
    __shared__ float sKt[128][17];  // keys tile, t-major, +1 pad
    __shared__ float sWo[64][17];   // W tile, o-major, +1 pad

    const int obase = blockIdx.x * 64;
    const int kbase = blockIdx.y * chunkLen;
    const int tid = threadIdx.x;
    const int ty = tid >> 4;   // 0..15 : t-group (8 t's each)
    const int tx = tid & 15;   // 0..15 : o-group (4 o's each)

    float acc[8][4];
    #pragma unroll
    for (int j = 0; j < 8; ++j)
        #pragma unroll
        for (int b = 0; b < 4; ++b) acc[j][b] = 0.f;

    const int nchunk = chunkLen >> 4;   // 16-wide k sub-chunks
    for (int c = 0; c < nchunk; ++c) {
        const int kb = kbase + c * 16;
        // stage keys[0:128, kb:kb+16] : 2048 floats = 2 float4/thread
        #pragma unroll
        for (int r = 0; r < 2; ++r) {
            const int idx = tid + r * 256;
            const int t = idx >> 2, q = idx & 3;
            float4 v = *reinterpret_cast<const float4*>(keys + t * D + kb + q * 4);
            sKt[t][q * 4 + 0] = v.x; sKt[t][q * 4 + 1] = v.y;
            sKt[t][q * 4 + 2] = v.z; sKt[t][q * 4 + 3] = v.w;
        }
        // stage W[obase:obase+64, kb:kb+16] : 1024 floats = 1 float4/thread
        {
            const int o = tid >> 2, q = tid & 3;
            float4 v = *reinterpret_cast<const float4*>(W + (obase + o) * D + kb + q * 4);
            sWo[o][q * 4 + 0] = v.x; sWo[o][q * 4 + 1] = v.y;
            sWo[o][q * 4 + 2] = v.z; sWo[o][q * 4 + 3] = v.w;
        }
        __syncthreads();

        #pragma unroll 4
        for (int k = 0; k < 16; ++k) {
            float kv[8], wv[4];
            #pragma unroll
            for (int j = 0; j < 8; ++j) kv[j] = sKt[ty * 8 + j][k];
            #pragma unroll
            for (int b = 0; b < 4; ++b) wv[b] = sWo[tx * 4 + b][k];
            #pragma unroll
            for (int j = 0; j < 8; ++j)
                #pragma unroll
                for (int b = 0; b < 4; ++b) acc[j][b] += kv[j] * wv[b];
        }
        __syncthreads();
    }

    float* outp = Ppart + blockIdx.y * (T * D);
    #pragma unroll
    for (int j = 0; j < 8; ++j) {
        const int t = ty * 8 + j;
        float4 v = { acc[j][0], acc[j][1], acc[j][2], acc[j][3] };
        *reinterpret_cast<float4*>(outp + t * D + obase + tx * 4) = v;
    }
}

// ---------------------------------------------------------------------------
// K2: combine partials -> errW tile; GEMM2 G = errW^T @ (2c*keys); fused
// W/mW epilogue. iT==0 blocks also emit b_new/mb_new; iT==1 blocks emit
// loss partials via atomicAdd (losses pre-zeroed by memset).
// grid = 144 (12 oT x 12 iT), 256 threads.
// ---------------------------------------------------------------------------
__global__ __launch_bounds__(256) void k2_main(
    const float* __restrict__ Ppart,
    const float* __restrict__ keys,
    const float* __restrict__ values,
    const float* __restrict__ W,
    const float* __restrict__ mW,
    const float* __restrict__ bparam,
    const float* __restrict__ mb,
    float* __restrict__ W_new,
    float* __restrict__ b_new,
    float* __restrict__ mW_new,
    float* __restrict__ mb_new,
    float* __restrict__ losses,
    int KC, float pow_eta_T, float beta_total, float Csum)
{
    __shared__ float sErr[T][64];   // errW[t, o-local]
    __shared__ float sKs[T][64];    // 2*c[t]*keys[t, i-local]
    __shared__ float sC[T];         // c[t]
    __shared__ float sB0[64];       // bparam[o-local]

    const int oT = blockIdx.x / 12, iT = blockIdx.x % 12;
    const int obase = oT * 64, ibase = iT * 64;
    const int tid = threadIdx.x;

    if (tid < T)  sC[tid]  = 0.01f * __expf((float)(127 - tid) * LN_ETA_DECAY);
    if (tid < 64) sB0[tid] = bparam[obase + tid];

    // stage: 128x64 tiles, 8 float4-groups per thread
    #pragma unroll
    for (int p = 0; p < 8; ++p) {
        const int idx = tid + p * 256;
        const int t = idx >> 4, q = idx & 15;
        float4 s = { 0.f, 0.f, 0.f, 0.f };
        for (int kc = 0; kc < KC; ++kc) {
            float4 v = *reinterpret_cast<const float4*>(
                Ppart + kc * (T * D) + t * D + obase + q * 4);
            s.x += v.x; s.y += v.y; s.z += v.z; s.w += v.w;
        }
        float4 vv = *reinterpret_cast<const float4*>(values + t * D + obase + q * 4);
        s.x -= vv.x; s.y -= vv.y; s.z -= vv.z; s.w -= vv.w;
        *reinterpret_cast<float4*>(&sErr[t][q * 4]) = s;

        const float c2 = 2.f * 0.01f * __expf((float)(127 - t) * LN_ETA_DECAY);
        float4 kv = *reinterpret_cast<const float4*>(keys + t * D + ibase + q * 4);
        kv.x *= c2; kv.y *= c2; kv.z *= c2; kv.w *= c2;
        *reinterpret_cast<float4*>(&sKs[t][q * 4]) = kv;
    }
    __syncthreads();

    const int ty = tid >> 4, tx = tid & 15;   // o-group, i-group
    float acc[4][4];
    #pragma unroll
    for (int a = 0; a < 4; ++a)
        #pragma unroll
        for (int b = 0; b < 4; ++b) acc[a][b] = 0.f;

    #pragma unroll 4
    for (int t = 0; t < T; ++t) {
        float4 a = *reinterpret_cast<const float4*>(&sErr[t][ty * 4]);
        float4 b = *reinterpret_cast<const float4*>(&sKs[t][tx * 4]);
        const float av[4] = { a.x, a.y, a.z, a.w };
        const float bv[4] = { b.x, b.y, b.z, b.w };
        #pragma unroll
        for (int aa = 0; aa < 4; ++aa)
            #pragma unroll
            for (int bb = 0; bb < 4; ++bb) acc[aa][bb] += av[aa] * bv[bb];
    }

    // W / mW epilogue: this block owns rows obase+ty*4..+3, cols ibase+tx*4..+3
    #pragma unroll
    for (int aa = 0; aa < 4; ++aa) {
        const int o = obase + ty * 4 + aa;
        const int i = ibase + tx * 4;
        float4 mv = *reinterpret_cast<const float4*>(mW + o * D + i);
        float4 wv = *reinterpret_cast<const float4*>(W + o * D + i);
        float4 nm, wn;
        nm.x = pow_eta_T * mv.x - acc[aa][0];
        nm.y = pow_eta_T * mv.y - acc[aa][1];
        nm.z = pow_eta_T * mv.z - acc[aa][2];
        nm.w = pow_eta_T * mv.w - acc[aa][3];
        wn.x = beta_total * wv.x + nm.x;
        wn.y = beta_total * wv.y + nm.y;
        wn.z = beta_total * wv.z + nm.z;
        wn.w = beta_total * wv.w + nm.w;
        *reinterpret_cast<float4*>(mW_new + o * D + i) = nm;
        *reinterpret_cast<float4*>(W_new + o * D + i) = wn;
    }

    // b epilogue (once per o-tile, on iT==0 blocks)
    if (iT == 0 && tid < 64) {
        float S = 0.f;
        for (int t = 0; t < T; ++t) S += sC[t] * sErr[t][tid];
        const int o = obase + tid;
        const float nmb = pow_eta_T * mb[o] - 2.f * S - 2.f * Csum * sB0[tid];
        mb_new[o] = nmb;
        b_new[o]  = beta_total * sB0[tid] + nmb;
    }

    // losses partial (once per o-tile, on iT==1 blocks):
    // losses[t] += (1/768) * sum_{o in tile} (errW[t,o]+b0[o])^2
    if (iT == 1) {
        const int t = tid >> 1, h = tid & 1;
        float L = 0.f;
        #pragma unroll 8
        for (int oo = 0; oo < 32; ++oo) {
            const int o = ((h * 32 + oo) + t) & 63;   // skew to dodge bank aliasing
            const float e = sErr[t][o] + sB0[o];
            L += e * e;
        }
        L += __shfl_xor(L, 1, 64);
        if (h == 0) atomicAdd(losses + t, L * (1.f / 768.f));
    }
}

extern "C" void kernel_launch(void* const* d_in, const int* in_sizes, int n_in,
                              void* d_out, int out_size, void* d_ws, size_t ws_size,
                              hipStream_t stream) {
    const float* W      = (const float*)d_in[0];
    const float* bparam = (const float*)d_in[1];
    const float* keys   = (const float*)d_in[2];
    const float* values = (const float*)d_in[3];
    const float* mW     = (const float*)d_in[4];
    const float* mb     = (const float*)d_in[5];

    float* out = (float*)d_out;
    float* W_new  = out;               // 768*768
    float* b_new  = out + 589824;      // 768
    float* mW_new = out + 590592;      // 768*768
    float* mb_new = out + 1180416;     // 768
    float* losses = out + 1181184;     // 128

    float* Ppart = (float*)d_ws;

    // pick largest KC in {8,6,4,3,2,1} whose partial buffers fit ws
    // (768/KC must be a multiple of 16 -> KC | 48)
    const size_t partBytes = (size_t)T * D * sizeof(float);  // 393216
    int KC = 1;
    const int cand[5] = { 8, 6, 4, 3, 2 };
    for (int c = 0; c < 5; ++c) {
        if ((size_t)cand[c] * partBytes <= ws_size) { KC = cand[c]; break; }
    }
    const int chunkLen = D / KC;

    double cs = 0.0;
    for (int t = 0; t < T; ++t) cs += 0.01 * pow(0.891, 127 - t);
    const float pow_eta_T  = (float)pow(0.9, 128);
    const float beta_total = (float)pow(0.99, 128);
    const float Csum = (float)cs;

    hipMemsetAsync(losses, 0, T * sizeof(float), stream);

    k1_pgemm<<<dim3(12, KC), 256, 0, stream>>>(W, keys, Ppart, chunkLen);
    k2_main<<<144, 256, 0, stream>>>(Ppart, keys, values, W, mW, bparam, mb,
                                     W_new, b_new, mW_new, mb_new, losses,
                                     KC, pow_eta_T, beta_total, Csum);
}

// Round 4
// 90.470 us; speedup vs baseline: 1.8584x; 1.2299x over previous
//
#include <hip/hip_runtime.h>
#include <math.h>

#define D 768
#define T 128
#define KC 8            // split-K chunks for GEMM1
#define CHUNKK (D / KC) // 96

// ln(0.9*0.99) = ln(0.891)
#define LN_ETA_DECAY (-0.11541085151132775f)

// ---------------------------------------------------------------------------
// K1: split-K partial GEMM  P = keys @ W^T   (M=128 t, N=768 o, K=768)
// grid = (12 o-tiles, KC k-chunks), 256 threads.
// LDS tiles are K-MAJOR so the inner loop is 3x ds_read_b128 + 32 FMA.
// Block (0,0) also zeroes losses (k2's atomicAdd target).
// ---------------------------------------------------------------------------
__global__ __launch_bounds__(256) void k1_pgemm(
    const float* __restrict__ W,
    const float* __restrict__ keys,
    float* __restrict__ Ppart,
    float* __restrict__ losses)
{
    __shared__ float sKt[16][132];  // [k][t], pitch 132: reads conflict-free
    __shared__ float sWo[16][68];   // [k][o], pitch 68

    const int obase = blockIdx.x * 64;
    const int kbase = blockIdx.y * CHUNKK;
    const int tid = threadIdx.x;
    const int ty = tid >> 4;   // 0..15 : t-group (8 t's)
    const int tx = tid & 15;   // 0..15 : o-group (4 o's)

    if (blockIdx.x == 0 && blockIdx.y == 0 && tid < T) losses[tid] = 0.f;

    float acc[8][4];
    #pragma unroll
    for (int j = 0; j < 8; ++j)
        #pragma unroll
        for (int b = 0; b < 4; ++b) acc[j][b] = 0.f;

    for (int c = 0; c < CHUNKK / 16; ++c) {
        const int kb = kbase + c * 16;
        // stage keys[0:128, kb:kb+16] -> sKt[k][t] (transpose in LDS)
        #pragma unroll
        for (int r = 0; r < 2; ++r) {
            const int idx = tid + r * 256;
            const int t = idx >> 2, q = idx & 3;
            float4 g = *reinterpret_cast<const float4*>(keys + t * D + kb + q * 4);
            sKt[q * 4 + 0][t] = g.x;
            sKt[q * 4 + 1][t] = g.y;
            sKt[q * 4 + 2][t] = g.z;
            sKt[q * 4 + 3][t] = g.w;
        }
        // stage W[obase:obase+64, kb:kb+16] -> sWo[k][o]
        {
            const int o = tid >> 2, q = tid & 3;
            float4 g = *reinterpret_cast<const float4*>(W + (obase + o) * D + kb + q * 4);
            sWo[q * 4 + 0][o] = g.x;
            sWo[q * 4 + 1][o] = g.y;
            sWo[q * 4 + 2][o] = g.z;
            sWo[q * 4 + 3][o] = g.w;
        }
        __syncthreads();

        #pragma unroll
        for (int k = 0; k < 16; ++k) {
            float4 a0 = *reinterpret_cast<const float4*>(&sKt[k][ty * 8]);
            float4 a1 = *reinterpret_cast<const float4*>(&sKt[k][ty * 8 + 4]);
            float4 b  = *reinterpret_cast<const float4*>(&sWo[k][tx * 4]);
            const float av[8] = { a0.x, a0.y, a0.z, a0.w, a1.x, a1.y, a1.z, a1.w };
            const float bv[4] = { b.x, b.y, b.z, b.w };
            #pragma unroll
            for (int j = 0; j < 8; ++j)
                #pragma unroll
                for (int n = 0; n < 4; ++n) acc[j][n] += av[j] * bv[n];
        }
        __syncthreads();
    }

    float* outp = Ppart + blockIdx.y * (T * D);
    #pragma unroll
    for (int j = 0; j < 8; ++j) {
        const int t = ty * 8 + j;
        float4 v = { acc[j][0], acc[j][1], acc[j][2], acc[j][3] };
        *reinterpret_cast<float4*>(outp + t * D + obase + tx * 4) = v;
    }
}

// ---------------------------------------------------------------------------
// K2: combine partials -> errW tile; GEMM2 G = errW^T @ (2c*keys); fused
// W/mW epilogue. iT==0 blocks also emit b_new/mb_new; iT==1 blocks emit
// loss partials via atomicAdd (losses zeroed by k1).
// grid = 144 (12 oT x 12 iT), 256 threads.
// ---------------------------------------------------------------------------
__global__ __launch_bounds__(256) void k2_main(
    const float* __restrict__ Ppart,
    const float* __restrict__ keys,
    const float* __restrict__ values,
    const float* __restrict__ W,
    const float* __restrict__ mW,
    const float* __restrict__ bparam,
    const float* __restrict__ mb,
    float* __restrict__ W_new,
    float* __restrict__ b_new,
    float* __restrict__ mW_new,
    float* __restrict__ mb_new,
    float* __restrict__ losses,
    float pow_eta_T, float beta_total, float Csum)
{
    __shared__ float sErr[T][64];   // errW[t, o-local]
    __shared__ float sKs[T][64];    // 2*c[t]*keys[t, i-local]
    __shared__ float sC[T];         // c[t]
    __shared__ float sB0[64];       // bparam[o-local]

    const int oT = blockIdx.x / 12, iT = blockIdx.x % 12;
    const int obase = oT * 64, ibase = iT * 64;
    const int tid = threadIdx.x;

    if (tid < T)  sC[tid]  = 0.01f * __expf((float)(127 - tid) * LN_ETA_DECAY);
    if (tid < 64) sB0[tid] = bparam[obase + tid];

    // stage: 128x64 tiles, 8 float4-groups per thread; combine KC partials
    #pragma unroll
    for (int p = 0; p < 8; ++p) {
        const int idx = tid + p * 256;
        const int t = idx >> 4, q = idx & 15;
        float4 s = { 0.f, 0.f, 0.f, 0.f };
        #pragma unroll
        for (int kc = 0; kc < KC; ++kc) {
            float4 v = *reinterpret_cast<const float4*>(
                Ppart + kc * (T * D) + t * D + obase + q * 4);
            s.x += v.x; s.y += v.y; s.z += v.z; s.w += v.w;
        }
        float4 vv = *reinterpret_cast<const float4*>(values + t * D + obase + q * 4);
        s.x -= vv.x; s.y -= vv.y; s.z -= vv.z; s.w -= vv.w;
        *reinterpret_cast<float4*>(&sErr[t][q * 4]) = s;

        const float c2 = 2.f * 0.01f * __expf((float)(127 - t) * LN_ETA_DECAY);
        float4 kv = *reinterpret_cast<const float4*>(keys + t * D + ibase + q * 4);
        kv.x *= c2; kv.y *= c2; kv.z *= c2; kv.w *= c2;
        *reinterpret_cast<float4*>(&sKs[t][q * 4]) = kv;
    }
    __syncthreads();

    const int ty = tid >> 4, tx = tid & 15;   // o-group, i-group
    float acc[4][4];
    #pragma unroll
    for (int a = 0; a < 4; ++a)
        #pragma unroll
        for (int b = 0; b < 4; ++b) acc[a][b] = 0.f;

    #pragma unroll 4
    for (int t = 0; t < T; ++t) {
        float4 a = *reinterpret_cast<const float4*>(&sErr[t][ty * 4]);
        float4 b = *reinterpret_cast<const float4*>(&sKs[t][tx * 4]);
        const float av[4] = { a.x, a.y, a.z, a.w };
        const float bv[4] = { b.x, b.y, b.z, b.w };
        #pragma unroll
        for (int aa = 0; aa < 4; ++aa)
            #pragma unroll
            for (int bb = 0; bb < 4; ++bb) acc[aa][bb] += av[aa] * bv[bb];
    }

    // W / mW epilogue: rows obase+ty*4..+3, cols ibase+tx*4..+3
    #pragma unroll
    for (int aa = 0; aa < 4; ++aa) {
        const int o = obase + ty * 4 + aa;
        const int i = ibase + tx * 4;
        float4 mv = *reinterpret_cast<const float4*>(mW + o * D + i);
        float4 wv = *reinterpret_cast<const float4*>(W + o * D + i);
        float4 nm, wn;
        nm.x = pow_eta_T * mv.x - acc[aa][0];
        nm.y = pow_eta_T * mv.y - acc[aa][1];
        nm.z = pow_eta_T * mv.z - acc[aa][2];
        nm.w = pow_eta_T * mv.w - acc[aa][3];
        wn.x = beta_total * wv.x + nm.x;
        wn.y = beta_total * wv.y + nm.y;
        wn.z = beta_total * wv.z + nm.z;
        wn.w = beta_total * wv.w + nm.w;
        *reinterpret_cast<float4*>(mW_new + o * D + i) = nm;
        *reinterpret_cast<float4*>(W_new + o * D + i) = wn;
    }

    // b epilogue (once per o-tile, on iT==0 blocks)
    if (iT == 0 && tid < 64) {
        float S = 0.f;
        for (int t = 0; t < T; ++t) S += sC[t] * sErr[t][tid];
        const int o = obase + tid;
        const float nmb = pow_eta_T * mb[o] - 2.f * S - 2.f * Csum * sB0[tid];
        mb_new[o] = nmb;
        b_new[o]  = beta_total * sB0[tid] + nmb;
    }

    // losses partial (once per o-tile, on iT==1 blocks):
    if (iT == 1) {
        const int t = tid >> 1, h = tid & 1;
        float L = 0.f;
        #pragma unroll 8
        for (int oo = 0; oo < 32; ++oo) {
            const int o = ((h * 32 + oo) + t) & 63;   // skew to dodge bank aliasing
            const float e = sErr[t][o] + sB0[o];
            L += e * e;
        }
        L += __shfl_xor(L, 1, 64);
        if (h == 0) atomicAdd(losses + t, L * (1.f / 768.f));
    }
}

extern "C" void kernel_launch(void* const* d_in, const int* in_sizes, int n_in,
                              void* d_out, int out_size, void* d_ws, size_t ws_size,
                              hipStream_t stream) {
    const float* W      = (const float*)d_in[0];
    const float* bparam = (const float*)d_in[1];
    const float* keys   = (const float*)d_in[2];
    const float* values = (const float*)d_in[3];
    const float* mW     = (const float*)d_in[4];
    const float* mb     = (const float*)d_in[5];

    float* out = (float*)d_out;
    float* W_new  = out;               // 768*768
    float* b_new  = out + 589824;      // 768
    float* mW_new = out + 590592;      // 768*768
    float* mb_new = out + 1180416;     // 768
    float* losses = out + 1181184;     // 128

    float* Ppart = (float*)d_ws;       // KC * 128*768 fp32 = 3.1 MB

    double cs = 0.0;
    for (int t = 0; t < T; ++t) cs += 0.01 * pow(0.891, 127 - t);
    const float pow_eta_T  = (float)pow(0.9, 128);
    const float beta_total = (float)pow(0.99, 128);
    const float Csum = (float)cs;

    k1_pgemm<<<dim3(12, KC), 256, 0, stream>>>(W, keys, Ppart, losses);
    k2_main<<<144, 256, 0, stream>>>(Ppart, keys, values, W, mW, bparam, mb,
                                     W_new, b_new, mW_new, mb_new, losses,
                                     pow_eta_T, beta_total, Csum);
}